// Round 4
// baseline (15000.523 us; speedup 1.0000x reference)
//
#include <hip/hip_runtime.h>

// LSTM  B=64, T=2048, I=H=512, fp32 in/out.
// Phase A: convert x to bf16; pack W_i (4 gates) transposed+bf16; bias.
// Phase B: Gx[t][j][bg][r][c] = x_t @ W_i + b  (bf16 MFMA GEMM, M=131072,N=2048,K=512)
// Phase C: persistent recurrence, 4 batch-groups x 8 col-wgs (32 wgs total).
//          Each wg: 64 h-cols x 4 gates, weights (256 VGPR/lane) pinned in regs.
//          Flag protocol (R2-proven): store h -> vmcnt(0) ack -> 1 flag store;
//          only wave0 polls 8 spaced flag lines. Minimal poll bytes, 8 parties.

typedef __attribute__((ext_vector_type(8))) short bf16x8;
typedef __attribute__((ext_vector_type(4))) float f32x4;

#define T_STEPS 2048
#define HB_STRIDE 32768   // shorts per h buffer: 4 bg * 16 rows * 512 cols

__device__ __forceinline__ unsigned short f2bf(float f) {
  union { float f; unsigned u; } v; v.f = f;
  unsigned r = v.u + 0x7fffu + ((v.u >> 16) & 1u);   // RNE
  return (unsigned short)(r >> 16);
}
__device__ __forceinline__ float bf2f(unsigned short b) {
  union { unsigned u; float f; } v; v.u = ((unsigned)b) << 16;
  return v.f;
}
__device__ __forceinline__ float sigm(float x)  { return 1.f / (1.f + __expf(-x)); }
__device__ __forceinline__ float tanhx(float x) { return 2.f / (1.f + __expf(-2.f * x)) - 1.f; }

// ---------------- Phase A: x fp32 -> bf16 ----------------
__global__ __launch_bounds__(256) void k_cvt(const float* __restrict__ x,
                                             unsigned short* __restrict__ xb, int n4) {
  int stride = gridDim.x * blockDim.x;
  for (int i = blockIdx.x * blockDim.x + threadIdx.x; i < n4; i += stride) {
    float4 v = ((const float4*)x)[i];
    ushort4 o;
    o.x = f2bf(v.x); o.y = f2bf(v.y); o.z = f2bf(v.z); o.w = f2bf(v.w);
    ((ushort4*)xb)[i] = o;
  }
}

// ---------------- Phase A: W_i -> Wt[p][k] bf16 (p = j*64 + g*16 + hl), bias ----------------
__global__ __launch_bounds__(128) void k_prep_w(
    const float* __restrict__ wi, const float* __restrict__ wf,
    const float* __restrict__ wg, const float* __restrict__ wo,
    const float* __restrict__ bii, const float* __restrict__ bif,
    const float* __restrict__ big, const float* __restrict__ bio,
    const float* __restrict__ bhi, const float* __restrict__ bhf,
    const float* __restrict__ bhg, const float* __restrict__ bho,
    unsigned short* __restrict__ Wt, float* __restrict__ biasp) {
  int p = blockIdx.x;
  int g = (p >> 4) & 3, jj = p >> 6, hl = p & 15;
  int hcol = jj * 16 + hl;
  const float* w = (g == 0) ? wi : (g == 1) ? wf : (g == 2) ? wg : wo;
  for (int k = threadIdx.x; k < 512; k += 128)
    Wt[(long)p * 512 + k] = f2bf(w[(long)k * 512 + hcol]);
  if (threadIdx.x == 0) {
    const float* bi = (g == 0) ? bii : (g == 1) ? bif : (g == 2) ? big : bio;
    const float* bh = (g == 0) ? bhi : (g == 1) ? bhf : (g == 2) ? bhg : bho;
    biasp[p] = bi[hcol] + bh[hcol];
  }
}

// ---------------- Phase B: Gx = x @ Wt^T + bias (bf16 MFMA, 128x128 tile, BK=64) ----------------
__global__ __launch_bounds__(256) void k_gemm_x(
    const unsigned short* __restrict__ A,   // [131072][512] bf16
    const unsigned short* __restrict__ Bt,  // [2048][512] bf16
    const float* __restrict__ biasp,        // [2048]
    unsigned short* __restrict__ Gx) {      // [T][32][4][16][64] bf16
  __shared__ unsigned short lds[16384];     // 32 KB: lA[128][64] | lB[128][64], reused for epilogue
  unsigned short* lA = lds;
  unsigned short* lB = lds + 8192;
  const int tid  = threadIdx.x;
  const int lane = tid & 63;
  const int wave = tid >> 6;
  const long m0  = (long)blockIdx.x * 128;
  const int p0   = blockIdx.y * 128;
  const int wm   = (wave >> 1) * 64;
  const int wn   = (wave & 1) * 64;
  const int lrow = lane & 15;
  const int quad = lane >> 4;

  f32x4 acc[4][4] = {};

  for (int kb = 0; kb < 512; kb += 64) {
    __syncthreads();
#pragma unroll
    for (int it = 0; it < 4; ++it) {          // stage 128 rows x 64 k, XOR-swizzled (16B units)
      int ci = it * 256 + tid;
      int row = ci >> 3, c8 = ci & 7;
      int c8p = c8 ^ (row & 7);
      *(int4*)&lA[row * 64 + c8p * 8] = *(const int4*)(A + (m0 + row) * 512 + kb + c8 * 8);
      *(int4*)&lB[row * 64 + c8p * 8] = *(const int4*)(Bt + (long)(p0 + row) * 512 + kb + c8 * 8);
    }
    __syncthreads();
#pragma unroll
    for (int kk = 0; kk < 2; ++kk) {
      int c8 = kk * 4 + quad;
      bf16x8 af[4], bfr[4];
#pragma unroll
      for (int i = 0; i < 4; ++i) {
        int m = wm + i * 16 + lrow;
        af[i]  = *(const bf16x8*)&lA[m * 64 + ((c8 ^ (m & 7)) * 8)];
        int p = wn + i * 16 + lrow;
        bfr[i] = *(const bf16x8*)&lB[p * 64 + ((c8 ^ (p & 7)) * 8)];
      }
#pragma unroll
      for (int i = 0; i < 4; ++i)
#pragma unroll
        for (int n = 0; n < 4; ++n)
          acc[i][n] = __builtin_amdgcn_mfma_f32_16x16x32_bf16(af[i], bfr[n], acc[i][n], 0, 0, 0);
    }
  }

  float bl[4];
#pragma unroll
  for (int n = 0; n < 4; ++n) bl[n] = biasp[p0 + wn + n * 16 + lrow];

  __syncthreads();
#pragma unroll
  for (int i = 0; i < 4; ++i)
#pragma unroll
    for (int n = 0; n < 4; ++n) {
      int col = wn + n * 16 + lrow;
#pragma unroll
      for (int r4 = 0; r4 < 4; ++r4) {
        int row = wm + i * 16 + quad * 4 + r4;          // C/D: col=lane&15, row=quad*4+reg
        lds[row * 128 + col] = f2bf(acc[i][n][r4] + bl[n]);
      }
    }
  __syncthreads();
  {
    int row = tid >> 1, half = tid & 1;
    long m = m0 + row;
    int b = (int)(m >> 11), t = (int)(m & 2047);
    int bg = b >> 4, r = b & 15;
    int jj = (p0 >> 6) + half;
    unsigned short* dst = Gx + ((((long)t * 32 + jj) * 4 + bg) * 16 + r) * 64;
    const unsigned short* src = lds + row * 128 + half * 64;
#pragma unroll
    for (int c = 0; c < 8; ++c)
      *(int4*)(dst + c * 8) = *(const int4*)(src + c * 8);
  }
}

// ---------------- Phase C: persistent recurrence, 8 parties/group ----------------
// 32 wgs = 4 batch-groups x 8 col-wgs. wg owns h-cols [j64*64, j64*64+64) x 4 gates.
// wave = gate. Weights: wfrag[ct 0..3][kt 0..15] pinned in VGPRs (256/lane).
__global__ __launch_bounds__(256, 1) void k_lstm(
    const float* __restrict__ Whi, const float* __restrict__ Whf,
    const float* __restrict__ Whg, const float* __restrict__ Who,
    const unsigned short* __restrict__ Gx,
    unsigned short* __restrict__ hbuf,   // [2][4 bg][16][512] bf16
    unsigned int* __restrict__ flags,    // [4 bg][8 slots x 16 dwords], zeroed
    float* __restrict__ out) {
  const int wg   = blockIdx.x;
  const int bg   = wg >> 3;
  const int j64  = wg & 7;
  const int tid  = threadIdx.x;
  const int lane = tid & 63;
  const int wave = tid >> 6;          // gate id
  const int hl   = lane & 15;
  const int quad = lane >> 4;

  __shared__ float gl[4][16][68];     // [gate][row r][local hcol], padded stride

  const float* Wh = (wave == 0) ? Whi : (wave == 1) ? Whf : (wave == 2) ? Whg : Who;
  union WFrag { bf16x8 v; unsigned u[4]; };
  WFrag wfrag[4][16];                 // [col-tile][k-tile]; B[k][n=lane&15]
#pragma unroll
  for (int ct = 0; ct < 4; ++ct) {
    int hcol = j64 * 64 + ct * 16 + hl;
#pragma unroll
    for (int kt = 0; kt < 16; ++kt) {
      int kbase = kt * 32 + quad * 8;
      bf16x8 t;
#pragma unroll
      for (int i = 0; i < 8; ++i)
        t[i] = (short)f2bf(Wh[(long)(kbase + i) * 512 + hcol]);
      wfrag[ct][kt].v = t;
    }
  }
  // Pin all weight fragments in VGPRs (defeat remat/sink).
#pragma unroll
  for (int ct = 0; ct < 4; ++ct)
#pragma unroll
    for (int kt = 0; kt < 16; ++kt)
#pragma unroll
      for (int r = 0; r < 4; ++r)
        asm volatile("" : "+v"(wfrag[ct][kt].u[r]));

  const int er  = tid >> 4;           // batch row within group (0..15)
  const int hc0 = (tid & 15) * 4;     // first of 4 local hcols owned by this thread
  const int r_a = lane & 15;          // MFMA A row
  const int jx  = j64 * 4 + (hc0 >> 4);
  const int clo = hc0 & 15;

  unsigned int* gflags = flags + bg * 128;

  float c_v[4] = {0.f, 0.f, 0.f, 0.f};
  float h_v[4] = {0.f, 0.f, 0.f, 0.f};

  for (int s = 0; s < T_STEPS; ++s) {
    // ---- sync-in: wave0 polls the group's 8 flags (8 lanes, 8 spaced lines) ----
    if (wave == 0 && s > 0) {
      for (;;) {
        unsigned v = 0xffffffffu;
        if (lane < 8)
          v = __hip_atomic_load(&gflags[lane * 16], __ATOMIC_RELAXED,
                                __HIP_MEMORY_SCOPE_AGENT);
        if (__all((int)(v >= (unsigned)s))) break;
        __builtin_amdgcn_s_sleep(1);
      }
    }
    __syncthreads();   // B1: release all waves once h_{s-1} is complete

    // ---- Gx loads for this step (normal cached loads, overlap af RT) ----
    const unsigned short* gxrow =
        Gx + (((long)s * 32 + jx) * 4 + bg) * 1024 + er * 64 + clo;
    ushort4 gx0 = *(const ushort4*)(gxrow);        // gate i
    ushort4 gx1 = *(const ushort4*)(gxrow + 16);   // gate f
    ushort4 gx2 = *(const ushort4*)(gxrow + 32);   // gate g
    ushort4 gx3 = *(const ushort4*)(gxrow + 48);   // gate o

    // ---- A fragments: full h_bg (16 rows x 512 cols), one-shot LLC loads ----
    bf16x8 af[16];
    if (s > 0) {
      const unsigned long long* hq = (const unsigned long long*)
          (hbuf + ((s - 1) & 1) * HB_STRIDE + (bg * 16 + r_a) * 512 + quad * 8);
#pragma unroll
      for (int kt = 0; kt < 16; ++kt) {
        union { unsigned long long q[2]; bf16x8 v; } u;
        u.q[0] = __hip_atomic_load(hq + kt * 8,     __ATOMIC_RELAXED, __HIP_MEMORY_SCOPE_AGENT);
        u.q[1] = __hip_atomic_load(hq + kt * 8 + 1, __ATOMIC_RELAXED, __HIP_MEMORY_SCOPE_AGENT);
        af[kt] = u.v;
      }
    } else {
      bf16x8 z = {0, 0, 0, 0, 0, 0, 0, 0};
#pragma unroll
      for (int kt = 0; kt < 16; ++kt) af[kt] = z;
    }

    // ---- 64 MFMAs: 4 independent col-tile chains, 16 deep ----
    f32x4 acc[4] = {};
#pragma unroll
    for (int kt = 0; kt < 16; ++kt)
#pragma unroll
      for (int ct = 0; ct < 4; ++ct)
        acc[ct] = __builtin_amdgcn_mfma_f32_16x16x32_bf16(af[kt], wfrag[ct][kt].v, acc[ct], 0, 0, 0);

    // ---- combine through LDS ----
#pragma unroll
    for (int ct = 0; ct < 4; ++ct)
#pragma unroll
      for (int i = 0; i < 4; ++i)
        gl[wave][quad * 4 + i][ct * 16 + hl] = acc[ct][i];   // C/D: col=lane&15, row=quad*4+reg
    __syncthreads();   // B2

    float4 gi = *(const float4*)&gl[0][er][hc0];
    float4 gf = *(const float4*)&gl[1][er][hc0];
    float4 gg = *(const float4*)&gl[2][er][hc0];
    float4 go = *(const float4*)&gl[3][er][hc0];
    const float* gip = (const float*)&gi;
    const float* gfp = (const float*)&gf;
    const float* ggp = (const float*)&gg;
    const float* gop = (const float*)&go;
    const unsigned short* g0 = (const unsigned short*)&gx0;
    const unsigned short* g1 = (const unsigned short*)&gx1;
    const unsigned short* g2 = (const unsigned short*)&gx2;
    const unsigned short* g3 = (const unsigned short*)&gx3;

    unsigned long long pack = 0;
#pragma unroll
    for (int c = 0; c < 4; ++c) {
      float ui = gip[c] + bf2f(g0[c]);
      float uf = gfp[c] + bf2f(g1[c]);
      float ug = ggp[c] + bf2f(g2[c]);
      float uo = gop[c] + bf2f(g3[c]);
      float ig = sigm(ui), fg = sigm(uf), gv = tanhx(ug), og = sigm(uo);
      c_v[c] = fg * c_v[c] + ig * gv;
      h_v[c] = og * tanhx(c_v[c]);
      pack |= ((unsigned long long)f2bf(h_v[c])) << (16 * c);
    }

    // ---- publish h slice: one 8B fire-and-forget store per thread ----
    {
      unsigned long long* hw =
          (unsigned long long*)(hbuf + (s & 1) * HB_STRIDE);
      __hip_atomic_store(hw + (((bg * 16 + er) * 512 + j64 * 64 + hc0) >> 2),
                         pack, __ATOMIC_RELAXED, __HIP_MEMORY_SCOPE_AGENT);
    }
    asm volatile("s_waitcnt vmcnt(0)" ::: "memory");   // own store acked at LLC
    __syncthreads();   // B3: all threads' stores acked
    if (tid == 0)
      __hip_atomic_store(&gflags[j64 * 16], (unsigned)(s + 1), __ATOMIC_RELAXED,
                         __HIP_MEMORY_SCOPE_AGENT);
  }

  int b = bg * 16 + er;
#pragma unroll
  for (int c = 0; c < 4; ++c) {
    out[(long)b * 512 + j64 * 64 + hc0 + c]         = h_v[c];   // h_T
    out[32768 + (long)b * 512 + j64 * 64 + hc0 + c] = c_v[c];   // c_T
  }
}

// ---------------- launcher ----------------
extern "C" void kernel_launch(void* const* d_in, const int* in_sizes, int n_in,
                              void* d_out, int out_size, void* d_ws, size_t ws_size,
                              hipStream_t stream) {
  const float* x    = (const float*)d_in[0];
  const float* w_ii = (const float*)d_in[1];
  const float* w_hi = (const float*)d_in[2];
  const float* b_ii = (const float*)d_in[3];
  const float* b_hi = (const float*)d_in[4];
  const float* w_if = (const float*)d_in[5];
  const float* w_hf = (const float*)d_in[6];
  const float* b_if_= (const float*)d_in[7];
  const float* b_hf = (const float*)d_in[8];
  const float* w_ig = (const float*)d_in[9];
  const float* w_hg = (const float*)d_in[10];
  const float* b_ig = (const float*)d_in[11];
  const float* b_hg = (const float*)d_in[12];
  const float* w_io = (const float*)d_in[13];
  const float* w_ho = (const float*)d_in[14];
  const float* b_io = (const float*)d_in[15];
  const float* b_ho = (const float*)d_in[16];

  char* ws = (char*)d_ws;
  // layout: Gx 512MB | xb 128MB | Wt 2MB | biasp 8KB | hbuf 128KB | flags 2KB
  unsigned short* Gx   = (unsigned short*)(ws);
  unsigned short* xb   = (unsigned short*)(ws + 536870912L);
  unsigned short* Wt   = (unsigned short*)(ws + 671088640L);
  float* biasp         = (float*)(ws + 673185792L);
  unsigned short* hbuf = (unsigned short*)(ws + 673193984L);
  unsigned int* flags  = (unsigned int*)(ws + 673193984L + 2L * HB_STRIDE * 2);

  hipMemsetAsync(flags, 0, 4 * 128 * sizeof(unsigned int), stream);

  k_cvt<<<8192, 256, 0, stream>>>(x, xb, (64 * 2048 * 512) / 4);
  k_prep_w<<<2048, 128, 0, stream>>>(w_ii, w_if, w_ig, w_io,
                                     b_ii, b_if_, b_ig, b_io,
                                     b_hi, b_hf, b_hg, b_ho,
                                     Wt, biasp);
  k_gemm_x<<<dim3(1024, 16), 256, 0, stream>>>(xb, Wt, biasp, Gx);
  k_lstm<<<32, 256, 0, stream>>>(w_hi, w_hf, w_hg, w_ho, Gx, hbuf, flags, (float*)d_out);
}